// Round 4
// baseline (117.099 us; speedup 1.0000x reference)
//
#include <hip/hip_runtime.h>

#define HALF   4096
#define NROWS  8192
#define DDIM   128
#define NGROUPS (NROWS / 128)                  // 64 row/col groups of 128
#define NPAIRS  (NGROUPS * (NGROUPS + 1) / 2)  // 2080 triangular tile-blocks
#define LDS_STRIDE 272                          // 256B row + 16B pad (conflict-free b128)

typedef _Float16 v8h __attribute__((ext_vector_type(8)));
typedef _Float16 v2h __attribute__((ext_vector_type(2)));
typedef float    v4f __attribute__((ext_vector_type(4)));

#if __has_builtin(__builtin_amdgcn_exp2f)
#define EXP2F(x) __builtin_amdgcn_exp2f(x)
#else
#define EXP2F(x) exp2f(x)
#endif
#if __has_builtin(__builtin_amdgcn_logf)
#define LOG2F(x) __builtin_amdgcn_logf(x)
#else
#define LOG2F(x) __log2f(x)
#endif

#define CEXP 2.8853900817779268f   // 2/ln2 : exp(2g-2) = 2^(CEXP*g - CEXP)

// ---------------- Kernel 1: row-normalize concat(z_i, z_j) -> fp16; zero S/acc/cnt
__global__ __launch_bounds__(256) void nt_normalize(
        const float* __restrict__ z_i, const float* __restrict__ z_j,
        _Float16* __restrict__ zn, float* __restrict__ S,
        float* __restrict__ acc, unsigned* __restrict__ cnt) {
    int tid  = threadIdx.x;
    int lane = tid & 63;
    int row  = blockIdx.x * 4 + (tid >> 6);
    // zero the accumulators later kernels atomicAdd into (ws is 0xAA-poisoned)
    if (tid < 4) S[blockIdx.x * 4 + tid] = 0.f;
    if (blockIdx.x == 0) {
        if (tid == 4) acc[0] = 0.f;
        if (tid == 5) cnt[0] = 0u;
    }

    const float* src = (row < HALF) ? (z_i + (size_t)row * DDIM)
                                    : (z_j + (size_t)(row - HALF) * DDIM);
    float2 v = *(const float2*)(src + lane * 2);
    float ss = v.x * v.x + v.y * v.y;
    #pragma unroll
    for (int off = 32; off >= 1; off >>= 1)
        ss += __shfl_xor(ss, off, 64);
    float inv = 1.0f / fmaxf(sqrtf(ss), 1e-8f);
    v2h p;
    p.x = (_Float16)(v.x * inv);
    p.y = (_Float16)(v.y * inv);
    *(v2h*)(zn + (size_t)row * DDIM + lane * 2) = p;
}

// ---------------- Kernel 2: symmetric Gram + shifted sum-exp, triangular tiles ----
// 2080 blocks = upper-triangle (I<=J) of the 64x64 grid of 128x128 tiles.
// 4 waves arranged 2x2: each wave owns 64 rows (16 A-frags in registers) x 64
// cols — halves LDS read traffic vs the 4x1 split. exp(sim) is symmetric, so
// off-diagonal tiles scatter row-sums AND column-sums into S. Partner-column
// exclusion is deferred to nt_correct. Shift M=2 bounds all logits, so
// partial sum-exps add directly (no online max).
__global__ __launch_bounds__(256, 3) void nt_gram_sym(
        const _Float16* __restrict__ zn, float* __restrict__ S) {
    __shared__ unsigned char lds[128 * LDS_STRIDE];   // 34816 B

    int tid  = threadIdx.x;
    int lane = tid & 63;
    int w    = tid >> 6;       // wave 0..3
    int wr   = w >> 1;         // wave-row 0..1
    int wc   = w & 1;          // wave-col 0..1
    int quad = lane >> 4;      // 0..3
    int cl   = lane & 15;      // 0..15

    // decode triangular pair index -> (I, J), I <= J
    int p = blockIdx.x;
    int J = (int)((sqrtf(8.0f * (float)p + 1.0f) - 1.0f) * 0.5f);
    while ((J + 1) * (J + 2) / 2 <= p) ++J;
    while (J * (J + 1) / 2 > p) --J;
    int I = p - J * (J + 1) / 2;
    int r0 = I * 128, c0 = J * 128;
    bool offdiag = (I != J);

    // A fragments: wave owns 64 rows (4 tiles of 16), kept in registers.
    // A-operand layout: lane holds A[m = lane&15][k = quad*8 + j]
    v8h a[4][4];
    #pragma unroll
    for (int u = 0; u < 4; ++u) {
        int arow = r0 + wr * 64 + u * 16 + cl;
        #pragma unroll
        for (int t = 0; t < 4; ++t)
            a[u][t] = *(const v8h*)(zn + (size_t)arow * DDIM + t * 32 + quad * 8);
    }

    // stage the 128-column tile (128 x 128 f16 = 32 KB) once, padded rows
    const uint4* gb = (const uint4*)zn;   // 1 uint4 = 8 f16
    #pragma unroll
    for (int i = 0; i < 8; ++i) {
        int rr = (tid >> 4) + i * 16;     // column index within tile
        uint4 v = gb[(size_t)(c0 + rr) * 16 + (tid & 15)];
        *(uint4*)&lds[(size_t)rr * LDS_STRIDE + (tid & 15) * 16] = v;
    }
    __syncthreads();

    float sums[4][4] = {{0.f,0.f,0.f,0.f},{0.f,0.f,0.f,0.f},
                        {0.f,0.f,0.f,0.f},{0.f,0.f,0.f,0.f}};

    #pragma unroll
    for (int sub = 0; sub < 4; ++sub) {
        v4f acc0 = {0.f,0.f,0.f,0.f}, acc1 = {0.f,0.f,0.f,0.f};
        v4f acc2 = {0.f,0.f,0.f,0.f}, acc3 = {0.f,0.f,0.f,0.f};
        #pragma unroll
        for (int t = 0; t < 4; ++t) {
            v8h b = *(const v8h*)&lds[(size_t)(wc * 64 + sub * 16 + cl) * LDS_STRIDE
                                      + t * 64 + quad * 16];
            acc0 = __builtin_amdgcn_mfma_f32_16x16x32_f16(a[0][t], b, acc0, 0, 0, 0);
            acc1 = __builtin_amdgcn_mfma_f32_16x16x32_f16(a[1][t], b, acc1, 0, 0, 0);
            acc2 = __builtin_amdgcn_mfma_f32_16x16x32_f16(a[2][t], b, acc2, 0, 0, 0);
            acc3 = __builtin_amdgcn_mfma_f32_16x16x32_f16(a[3][t], b, acc3, 0, 0, 0);
        }
        // epilogue: exp(2g-2); row sums in regs, column sums cross-lane
        float cp = 0.f;
        #pragma unroll
        for (int r = 0; r < 4; ++r) {
            float e0 = EXP2F(fmaf(acc0[r], CEXP, -CEXP));
            float e1 = EXP2F(fmaf(acc1[r], CEXP, -CEXP));
            float e2 = EXP2F(fmaf(acc2[r], CEXP, -CEXP));
            float e3 = EXP2F(fmaf(acc3[r], CEXP, -CEXP));
            sums[0][r] += e0; sums[1][r] += e1;
            sums[2][r] += e2; sums[3][r] += e3;
            cp += (e0 + e1) + (e2 + e3);
        }
        if (offdiag) {
            // column sums over this wave's 64 rows (reduce across quads)
            cp += __shfl_xor(cp, 16, 64);
            cp += __shfl_xor(cp, 32, 64);
            if (quad == 0)
                atomicAdd(&S[c0 + wc * 64 + sub * 16 + cl], cp);
        }
    }

    // row sums: reduce across the 16 column-lanes, one atomic per row per wave
    #pragma unroll
    for (int u = 0; u < 4; ++u)
        #pragma unroll
        for (int r = 0; r < 4; ++r) {
            float s = sums[u][r];
            #pragma unroll
            for (int off = 1; off < 16; off <<= 1)
                s += __shfl_xor(s, off, 64);
            if (cl == 0)
                atomicAdd(&S[r0 + wr * 64 + u * 16 + quad * 4 + r], s);
        }
}

// ---------------- Kernel 3: subtract partner term, log, reduce, finalize -------
// one wave per row-pair (r, r+HALF): recompute dot(zn[r], zn[r+HALF]) in fp32,
// subtract its exp from both rows' sums, log2, block-reduce, atomicAdd into
// acc. The LAST block (done-counter) scales and writes the loss — saves a
// separate finalize launch.
__global__ __launch_bounds__(256) void nt_correct(
        const _Float16* __restrict__ zn, const float* __restrict__ S,
        float* __restrict__ acc, unsigned* __restrict__ cnt,
        float* __restrict__ out) {
    int tid  = threadIdx.x;
    int lane = tid & 63;
    int w    = tid >> 6;
    int pr   = blockIdx.x * 4 + w;   // pair 0..4095

    v2h xa = *(const v2h*)(zn + (size_t)pr * DDIM + lane * 2);
    v2h xb = *(const v2h*)(zn + (size_t)(pr + HALF) * DDIM + lane * 2);
    float d = (float)xa.x * (float)xb.x + (float)xa.y * (float)xb.y;
    #pragma unroll
    for (int off = 32; off >= 1; off >>= 1)
        d += __shfl_xor(d, off, 64);

    __shared__ float red[4];
    if (lane == 0) {
        float e = EXP2F(fmaf(d, CEXP, -CEXP));
        red[w] = LOG2F(S[pr] - e) + LOG2F(S[pr + HALF] - e);
    }
    __syncthreads();
    if (tid == 0) {
        atomicAdd(acc, red[0] + red[1] + red[2] + red[3]);
        __threadfence();
        unsigned old = atomicAdd(cnt, 1u);
        if (old == gridDim.x - 1) {   // last block: all acc adds visible
            float total = atomicAdd(acc, 0.f);   // device-coherent read
            out[0] = total * (0.69314718055994531f / (float)NROWS);
        }
    }
}

extern "C" void kernel_launch(void* const* d_in, const int* in_sizes, int n_in,
                              void* d_out, int out_size, void* d_ws, size_t ws_size,
                              hipStream_t stream) {
    const float* z_i = (const float*)d_in[0];
    const float* z_j = (const float*)d_in[1];
    _Float16* zn  = (_Float16*)d_ws;                                    // 2 MB
    float*    S   = (float*)((char*)d_ws + (size_t)NROWS * DDIM * 2);   // 8192 f32
    float*    acc = S + NROWS;                                          // 1 f32
    unsigned* cnt = (unsigned*)(acc + 1);                               // 1 u32
    float*    out = (float*)d_out;

    nt_normalize<<<dim3(NROWS / 4), dim3(256), 0, stream>>>(z_i, z_j, zn, S, acc, cnt);
    nt_gram_sym<<<dim3(NPAIRS), dim3(256), 0, stream>>>(zn, S);
    nt_correct<<<dim3(HALF / 4), dim3(256), 0, stream>>>(zn, S, acc, cnt, out);
}

// Round 5
// 112.060 us; speedup vs baseline: 1.0450x; 1.0450x over previous
//
#include <hip/hip_runtime.h>

#define HALF   4096
#define NROWS  8192
#define DDIM   128
#define NGROUPS (NROWS / 128)                  // 64 row/col groups of 128
#define NPAIRS  (NGROUPS * (NGROUPS + 1) / 2)  // 2080 triangular tile-blocks
#define LDS_STRIDE 272                          // 256B row + 16B pad (conflict-free b128)

typedef _Float16 v8h __attribute__((ext_vector_type(8)));
typedef _Float16 v2h __attribute__((ext_vector_type(2)));
typedef float    v4f __attribute__((ext_vector_type(4)));

#if __has_builtin(__builtin_amdgcn_exp2f)
#define EXP2F(x) __builtin_amdgcn_exp2f(x)
#else
#define EXP2F(x) exp2f(x)
#endif
#if __has_builtin(__builtin_amdgcn_logf)
#define LOG2F(x) __builtin_amdgcn_logf(x)
#else
#define LOG2F(x) __log2f(x)
#endif

#define CEXP 2.8853900817779268f   // 2/ln2 : exp(2g-2) = 2^(CEXP*g - CEXP)

// ---------------- Kernel 1: row-normalize concat(z_i, z_j) -> fp16; zero S/acc/cnt
__global__ __launch_bounds__(256) void nt_normalize(
        const float* __restrict__ z_i, const float* __restrict__ z_j,
        _Float16* __restrict__ zn, float* __restrict__ S,
        float* __restrict__ acc, unsigned* __restrict__ cnt) {
    int tid  = threadIdx.x;
    int lane = tid & 63;
    int row  = blockIdx.x * 4 + (tid >> 6);
    // zero the accumulators later kernels atomicAdd into (ws is 0xAA-poisoned)
    if (tid < 4) S[blockIdx.x * 4 + tid] = 0.f;
    if (blockIdx.x == 0) {
        if (tid == 4) acc[0] = 0.f;
        if (tid == 5) cnt[0] = 0u;
    }

    const float* src = (row < HALF) ? (z_i + (size_t)row * DDIM)
                                    : (z_j + (size_t)(row - HALF) * DDIM);
    float2 v = *(const float2*)(src + lane * 2);
    float ss = v.x * v.x + v.y * v.y;
    #pragma unroll
    for (int off = 32; off >= 1; off >>= 1)
        ss += __shfl_xor(ss, off, 64);
    float inv = 1.0f / fmaxf(sqrtf(ss), 1e-8f);
    v2h p;
    p.x = (_Float16)(v.x * inv);
    p.y = (_Float16)(v.y * inv);
    *(v2h*)(zn + (size_t)row * DDIM + lane * 2) = p;
}

// ---------------- Kernel 2: symmetric Gram + shifted sum-exp, triangular tiles ----
// 2080 blocks = upper-triangle (I<=J) of the 64x64 grid of 128x128 tiles.
// R3-proven shape: 4 waves each own 32 rows (a[2][4] = 32 VGPRs of A-frags,
// 2 live accumulators) x all 128 cols; 8 column-subtiles. (R4's 2x2 wave
// tiling with a[4][4] regressed — register pressure beat the LDS savings.)
// exp(sim) is symmetric: off-diagonal tiles scatter row-sums AND column-sums
// into S. Partner exclusion deferred to nt_correct. Shift M=2 bounds all
// logits, so partial sum-exps add directly (no online max needed).
__global__ __launch_bounds__(256, 4) void nt_gram_sym(
        const _Float16* __restrict__ zn, float* __restrict__ S) {
    __shared__ unsigned char lds[128 * LDS_STRIDE];   // 34816 B

    int tid  = threadIdx.x;
    int lane = tid & 63;
    int w    = tid >> 6;       // wave 0..3
    int quad = lane >> 4;      // 0..3
    int cl   = lane & 15;      // 0..15

    // decode triangular pair index -> (I, J), I <= J
    int p = blockIdx.x;
    int J = (int)((sqrtf(8.0f * (float)p + 1.0f) - 1.0f) * 0.5f);
    while ((J + 1) * (J + 2) / 2 <= p) ++J;
    while (J * (J + 1) / 2 > p) --J;
    int I = p - J * (J + 1) / 2;
    int r0 = I * 128, c0 = J * 128;
    bool offdiag = (I != J);

    // A fragments: wave w owns 32 rows (2 tiles of 16), kept in registers.
    // A-operand layout: lane holds A[m = lane&15][k = quad*8 + j]
    v8h a[2][4];
    #pragma unroll
    for (int u = 0; u < 2; ++u) {
        int arow = r0 + w * 32 + u * 16 + cl;
        #pragma unroll
        for (int t = 0; t < 4; ++t)
            a[u][t] = *(const v8h*)(zn + (size_t)arow * DDIM + t * 32 + quad * 8);
    }

    // stage the 128-column tile (128 x 128 f16 = 32 KB) once, padded rows
    const uint4* gb = (const uint4*)zn;   // 1 uint4 = 8 f16
    #pragma unroll
    for (int i = 0; i < 8; ++i) {
        int rr = (tid >> 4) + i * 16;     // column index within tile
        uint4 v = gb[(size_t)(c0 + rr) * 16 + (tid & 15)];
        *(uint4*)&lds[(size_t)rr * LDS_STRIDE + (tid & 15) * 16] = v;
    }
    __syncthreads();

    float sums[2][4] = {{0.f,0.f,0.f,0.f},{0.f,0.f,0.f,0.f}};

    #pragma unroll
    for (int sub = 0; sub < 8; ++sub) {
        v4f acc0 = {0.f, 0.f, 0.f, 0.f};
        v4f acc1 = {0.f, 0.f, 0.f, 0.f};
        #pragma unroll
        for (int t = 0; t < 4; ++t) {
            v8h b = *(const v8h*)&lds[(size_t)(sub * 16 + cl) * LDS_STRIDE + t * 64 + quad * 16];
            acc0 = __builtin_amdgcn_mfma_f32_16x16x32_f16(a[0][t], b, acc0, 0, 0, 0);
            acc1 = __builtin_amdgcn_mfma_f32_16x16x32_f16(a[1][t], b, acc1, 0, 0, 0);
        }
        // epilogue: exp(2g-2); row sums in regs, column sums cross-lane
        float cp = 0.f;
        #pragma unroll
        for (int r = 0; r < 4; ++r) {
            float e0 = EXP2F(fmaf(acc0[r], CEXP, -CEXP));
            float e1 = EXP2F(fmaf(acc1[r], CEXP, -CEXP));
            sums[0][r] += e0;
            sums[1][r] += e1;
            cp += e0 + e1;
        }
        if (offdiag) {
            // column sums: reduce over the wave's 32 rows (across quads)
            cp += __shfl_xor(cp, 16, 64);
            cp += __shfl_xor(cp, 32, 64);
            if (quad == 0)
                atomicAdd(&S[c0 + sub * 16 + cl], cp);
        }
    }

    // row sums: reduce across the 16 column-lanes, one atomic per row
    #pragma unroll
    for (int u = 0; u < 2; ++u)
        #pragma unroll
        for (int r = 0; r < 4; ++r) {
            float s = sums[u][r];
            #pragma unroll
            for (int off = 1; off < 16; off <<= 1)
                s += __shfl_xor(s, off, 64);
            if (cl == 0)
                atomicAdd(&S[r0 + w * 32 + u * 16 + quad * 4 + r], s);
        }
}

// ---------------- Kernel 3: subtract partner term, log, reduce, finalize -------
// one wave per row-pair (r, r+HALF): recompute dot(zn[r], zn[r+HALF]) in fp32,
// subtract its exp from both rows' sums, log2, block-reduce, atomicAdd into
// acc. The LAST block (done-counter) scales and writes the loss.
__global__ __launch_bounds__(256) void nt_correct(
        const _Float16* __restrict__ zn, const float* __restrict__ S,
        float* __restrict__ acc, unsigned* __restrict__ cnt,
        float* __restrict__ out) {
    int tid  = threadIdx.x;
    int lane = tid & 63;
    int w    = tid >> 6;
    int pr   = blockIdx.x * 4 + w;   // pair 0..4095

    v2h xa = *(const v2h*)(zn + (size_t)pr * DDIM + lane * 2);
    v2h xb = *(const v2h*)(zn + (size_t)(pr + HALF) * DDIM + lane * 2);
    float d = (float)xa.x * (float)xb.x + (float)xa.y * (float)xb.y;
    #pragma unroll
    for (int off = 32; off >= 1; off >>= 1)
        d += __shfl_xor(d, off, 64);

    __shared__ float red[4];
    if (lane == 0) {
        float e = EXP2F(fmaf(d, CEXP, -CEXP));
        red[w] = LOG2F(S[pr] - e) + LOG2F(S[pr + HALF] - e);
    }
    __syncthreads();
    if (tid == 0) {
        atomicAdd(acc, red[0] + red[1] + red[2] + red[3]);
        __threadfence();
        unsigned old = atomicAdd(cnt, 1u);
        if (old == gridDim.x - 1) {   // last block: all acc adds visible
            float total = atomicAdd(acc, 0.f);   // device-coherent read
            out[0] = total * (0.69314718055994531f / (float)NROWS);
        }
    }
}

extern "C" void kernel_launch(void* const* d_in, const int* in_sizes, int n_in,
                              void* d_out, int out_size, void* d_ws, size_t ws_size,
                              hipStream_t stream) {
    const float* z_i = (const float*)d_in[0];
    const float* z_j = (const float*)d_in[1];
    _Float16* zn  = (_Float16*)d_ws;                                    // 2 MB
    float*    S   = (float*)((char*)d_ws + (size_t)NROWS * DDIM * 2);   // 8192 f32
    float*    acc = S + NROWS;                                          // 1 f32
    unsigned* cnt = (unsigned*)(acc + 1);                               // 1 u32
    float*    out = (float*)d_out;

    nt_normalize<<<dim3(NROWS / 4), dim3(256), 0, stream>>>(z_i, z_j, zn, S, acc, cnt);
    nt_gram_sym<<<dim3(NPAIRS), dim3(256), 0, stream>>>(zn, S);
    nt_correct<<<dim3(HALF / 4), dim3(256), 0, stream>>>(zn, S, acc, cnt, out);
}

// Round 6
// 93.872 us; speedup vs baseline: 1.2474x; 1.1938x over previous
//
#include <hip/hip_runtime.h>

#define HALF   4096
#define NROWS  8192
#define DDIM   128
#define NGROUPS (NROWS / 128)                  // 64 row/col groups of 128
#define NPAIRS  (NGROUPS * (NGROUPS + 1) / 2)  // 2080 triangular tile-blocks
#define LDS_STRIDE 272                          // 256B row + 16B pad (conflict-free b128)

typedef _Float16 v8h __attribute__((ext_vector_type(8)));
typedef _Float16 v2h __attribute__((ext_vector_type(2)));
typedef float    v4f __attribute__((ext_vector_type(4)));

#if __has_builtin(__builtin_amdgcn_exp2f)
#define EXP2F(x) __builtin_amdgcn_exp2f(x)
#else
#define EXP2F(x) exp2f(x)
#endif
#if __has_builtin(__builtin_amdgcn_logf)
#define LOG2F(x) __builtin_amdgcn_logf(x)
#else
#define LOG2F(x) __log2f(x)
#endif

#define CEXP 2.8853900817779268f   // 2/ln2 : exp(2g-2) = 2^(CEXP*g - CEXP)

// ---------------- Kernel 1: row-normalize concat(z_i, z_j) -> fp16; zero S/acc ----
__global__ __launch_bounds__(256) void nt_normalize(
        const float* __restrict__ z_i, const float* __restrict__ z_j,
        _Float16* __restrict__ zn, float* __restrict__ S, float* __restrict__ acc) {
    int tid  = threadIdx.x;
    int lane = tid & 63;
    int row  = blockIdx.x * 4 + (tid >> 6);
    // zero the accumulators later kernels atomicAdd into (ws is 0xAA-poisoned)
    if (tid < 4) S[blockIdx.x * 4 + tid] = 0.f;
    if (blockIdx.x == 0 && tid == 4) acc[0] = 0.f;

    const float* src = (row < HALF) ? (z_i + (size_t)row * DDIM)
                                    : (z_j + (size_t)(row - HALF) * DDIM);
    float2 v = *(const float2*)(src + lane * 2);
    float ss = v.x * v.x + v.y * v.y;
    #pragma unroll
    for (int off = 32; off >= 1; off >>= 1)
        ss += __shfl_xor(ss, off, 64);
    float inv = 1.0f / fmaxf(sqrtf(ss), 1e-8f);
    v2h p;
    p.x = (_Float16)(v.x * inv);
    p.y = (_Float16)(v.y * inv);
    *(v2h*)(zn + (size_t)row * DDIM + lane * 2) = p;
}

// ---------------- Kernel 2: symmetric Gram + shifted sum-exp, triangular tiles ----
// 2080 blocks = upper-triangle (I<=J) of the 64x64 grid of 128x128 tiles.
// R3-proven shape: 4 waves each own 32 rows (a[2][4] = 32 VGPRs of A-frags,
// 2 live accumulators) x all 128 cols; 8 column-subtiles. (2x2 wave tiling
// with a[4][4] regressed — register pressure beat the LDS savings.)
// exp(sim) is symmetric: off-diagonal tiles scatter row-sums AND column-sums
// into S. Partner exclusion deferred to nt_correct. Shift M=2 bounds all
// logits, so partial sum-exps add directly (no online max needed).
__global__ __launch_bounds__(256, 4) void nt_gram_sym(
        const _Float16* __restrict__ zn, float* __restrict__ S) {
    __shared__ unsigned char lds[128 * LDS_STRIDE];   // 34816 B

    int tid  = threadIdx.x;
    int lane = tid & 63;
    int w    = tid >> 6;       // wave 0..3
    int quad = lane >> 4;      // 0..3
    int cl   = lane & 15;      // 0..15

    // decode triangular pair index -> (I, J), I <= J
    int p = blockIdx.x;
    int J = (int)((sqrtf(8.0f * (float)p + 1.0f) - 1.0f) * 0.5f);
    while ((J + 1) * (J + 2) / 2 <= p) ++J;
    while (J * (J + 1) / 2 > p) --J;
    int I = p - J * (J + 1) / 2;
    int r0 = I * 128, c0 = J * 128;
    bool offdiag = (I != J);

    // A fragments: wave w owns 32 rows (2 tiles of 16), kept in registers.
    // A-operand layout: lane holds A[m = lane&15][k = quad*8 + j]
    v8h a[2][4];
    #pragma unroll
    for (int u = 0; u < 2; ++u) {
        int arow = r0 + w * 32 + u * 16 + cl;
        #pragma unroll
        for (int t = 0; t < 4; ++t)
            a[u][t] = *(const v8h*)(zn + (size_t)arow * DDIM + t * 32 + quad * 8);
    }

    // stage the 128-column tile (128 x 128 f16 = 32 KB) once, padded rows
    const uint4* gb = (const uint4*)zn;   // 1 uint4 = 8 f16
    #pragma unroll
    for (int i = 0; i < 8; ++i) {
        int rr = (tid >> 4) + i * 16;     // column index within tile
        uint4 v = gb[(size_t)(c0 + rr) * 16 + (tid & 15)];
        *(uint4*)&lds[(size_t)rr * LDS_STRIDE + (tid & 15) * 16] = v;
    }
    __syncthreads();

    float sums[2][4] = {{0.f,0.f,0.f,0.f},{0.f,0.f,0.f,0.f}};

    #pragma unroll
    for (int sub = 0; sub < 8; ++sub) {
        v4f acc0 = {0.f, 0.f, 0.f, 0.f};
        v4f acc1 = {0.f, 0.f, 0.f, 0.f};
        #pragma unroll
        for (int t = 0; t < 4; ++t) {
            v8h b = *(const v8h*)&lds[(size_t)(sub * 16 + cl) * LDS_STRIDE + t * 64 + quad * 16];
            acc0 = __builtin_amdgcn_mfma_f32_16x16x32_f16(a[0][t], b, acc0, 0, 0, 0);
            acc1 = __builtin_amdgcn_mfma_f32_16x16x32_f16(a[1][t], b, acc1, 0, 0, 0);
        }
        // epilogue: exp(2g-2); row sums in regs, column sums cross-lane
        float cp = 0.f;
        #pragma unroll
        for (int r = 0; r < 4; ++r) {
            float e0 = EXP2F(fmaf(acc0[r], CEXP, -CEXP));
            float e1 = EXP2F(fmaf(acc1[r], CEXP, -CEXP));
            sums[0][r] += e0;
            sums[1][r] += e1;
            cp += e0 + e1;
        }
        if (offdiag) {
            // column sums: reduce over the wave's 32 rows (across quads)
            cp += __shfl_xor(cp, 16, 64);
            cp += __shfl_xor(cp, 32, 64);
            if (quad == 0)
                atomicAdd(&S[c0 + sub * 16 + cl], cp);
        }
    }

    // row sums: reduce across the 16 column-lanes, one atomic per row
    #pragma unroll
    for (int u = 0; u < 2; ++u)
        #pragma unroll
        for (int r = 0; r < 4; ++r) {
            float s = sums[u][r];
            #pragma unroll
            for (int off = 1; off < 16; off <<= 1)
                s += __shfl_xor(s, off, 64);
            if (cl == 0)
                atomicAdd(&S[r0 + w * 32 + u * 16 + quad * 4 + r], s);
        }
}

// ---------------- Kernel 3: subtract partner term, log, reduce ----------------
// 64 blocks x 64 pairs: each wave handles 16 pairs sequentially (fp32 dot of
// the f16 rows, 64-lane butterfly reduce), accumulates its log terms locally,
// then ONE atomicAdd per block — 64 contended atomics total (vs 1024 in R3,
// which cost ~5 µs of serialization; the R5 fused-finalize variant with 2048
// single-address atomics + fences cost ~9 µs and was reverted).
__global__ __launch_bounds__(256) void nt_correct(
        const _Float16* __restrict__ zn, const float* __restrict__ S,
        float* __restrict__ acc) {
    int tid  = threadIdx.x;
    int lane = tid & 63;
    int w    = tid >> 6;

    float part = 0.f;   // lane 0 of each wave accumulates
    #pragma unroll 1
    for (int q = 0; q < 16; ++q) {
        int pr = (blockIdx.x * 4 + w) * 16 + q;   // pair 0..4095
        v2h xa = *(const v2h*)(zn + (size_t)pr * DDIM + lane * 2);
        v2h xb = *(const v2h*)(zn + (size_t)(pr + HALF) * DDIM + lane * 2);
        float d = (float)xa.x * (float)xb.x + (float)xa.y * (float)xb.y;
        #pragma unroll
        for (int off = 32; off >= 1; off >>= 1)
            d += __shfl_xor(d, off, 64);
        if (lane == 0) {
            float e = EXP2F(fmaf(d, CEXP, -CEXP));
            part += LOG2F(S[pr] - e) + LOG2F(S[pr + HALF] - e);
        }
    }

    __shared__ float red[4];
    if (lane == 0) red[w] = part;
    __syncthreads();
    if (tid == 0)
        atomicAdd(acc, red[0] + red[1] + red[2] + red[3]);
}

// ---------------- Kernel 4: final scale ----------------
__global__ void nt_final(const float* __restrict__ acc, float* __restrict__ out) {
    out[0] = acc[0] * (0.69314718055994531f / (float)NROWS);
}

extern "C" void kernel_launch(void* const* d_in, const int* in_sizes, int n_in,
                              void* d_out, int out_size, void* d_ws, size_t ws_size,
                              hipStream_t stream) {
    const float* z_i = (const float*)d_in[0];
    const float* z_j = (const float*)d_in[1];
    _Float16* zn  = (_Float16*)d_ws;                                    // 2 MB
    float*    S   = (float*)((char*)d_ws + (size_t)NROWS * DDIM * 2);   // 8192 f32
    float*    acc = S + NROWS;                                          // 1 f32
    float*    out = (float*)d_out;

    nt_normalize<<<dim3(NROWS / 4), dim3(256), 0, stream>>>(z_i, z_j, zn, S, acc);
    nt_gram_sym<<<dim3(NPAIRS), dim3(256), 0, stream>>>(zn, S);
    nt_correct<<<dim3(HALF / 64), dim3(256), 0, stream>>>(zn, S, acc);
    nt_final<<<dim3(1), dim3(1), 0, stream>>>(acc, out);
}